// Round 17
// baseline (338.956 us; speedup 1.0000x reference)
//
#include <hip/hip_runtime.h>

#define N_NODES 100000
#define D 128
#define E_EDGES 3200000
#define BSHIFT 8
#define NPB 256                  // nodes per bin
#define NBIN 391                 // ceil(N_NODES / 256)
#define BCAP 8960                // per-bin capacity: mean 8192 + 8.5 sigma
#define PBLK 625
#define CHUNK 5120               // edges per partition block (int4-friendly)

typedef short bf16x8 __attribute__((ext_vector_type(8)));
typedef float f32x4 __attribute__((ext_vector_type(4)));

__device__ __forceinline__ unsigned rne_bf16(float f) {   // fp32 -> bf16 (RNE), low 16
    unsigned u = __float_as_uint(f);
    return (u + 0x7FFFu + ((u >> 16) & 1u)) >> 16;
}
__device__ __forceinline__ float bf_lo(unsigned u) { return __uint_as_float(u << 16); }
__device__ __forceinline__ float bf_hi(unsigned u) { return __uint_as_float(u & 0xFFFF0000u); }

// ---------------- kernel 1: xb = bf16(x), + Wt prep + ctrl zero (fused) -----------
// R13: weights in FRAGMENT-LOAD order (mlp weight loads fully coalesced).
// R14: float4 loads (16B/lane), 12500 blocks. KEPT (likely neutral/positive).
__global__ __launch_bounds__(256) void prep(const float* __restrict__ x,
                                            const float* __restrict__ W1,
                                            const float* __restrict__ W2,
                                            const float* __restrict__ W3,
                                            unsigned* __restrict__ xb,
                                            unsigned short* __restrict__ wt,
                                            int* __restrict__ ctrl) {
    int i = blockIdx.x * 256 + threadIdx.x;    // 12500 blocks: 3.2M float4
    float4 v = ((const float4*)x)[i];
    uint2 o;
    o.x = rne_bf16(v.x) | (rne_bf16(v.y) << 16);
    o.y = rne_bf16(v.z) | (rne_bf16(v.w) << 16);
    ((uint2*)xb)[i] = o;
    if (i < 1024) ctrl[i] = 0;                 // gcnt@0, gpos@dword512
    if (i < 3 * 16384) {
        int l = i >> 14, o2 = i & 16383;
        int j = o2 & 7, lane = (o2 >> 3) & 63, ks = (o2 >> 9) & 3, ct = (o2 >> 11) & 7;
        int m = lane & 15, quad = lane >> 4;
        int r = (ks * 32 + quad * 8 + j) * 128 + ct * 16 + m;
        const float* W = l == 0 ? W1 : (l == 1 ? W2 : W3);
        wt[l * 16384 + o2] = (unsigned short)rne_bf16(W[r]);
    }
}

// ---------------- kernel 2: bin edges by dst>>8 (de-staged, R14) ------------------
// R14: dropped ssrc/sdst LDS staging (41KB -> 3KB, 3 -> 8 blocks/CU). KEPT —
// R16 A/B attributes the R14 regression; csr@512 is the prime suspect.
__global__ __launch_bounds__(256) void partition_edges(const int* __restrict__ eidx,
                                                       int* __restrict__ gcnt,
                                                       unsigned* __restrict__ bbuf) {
    __shared__ int hist[NBIN];
    __shared__ int cur[NBIN];
    int tid = threadIdx.x;
    for (int i = tid; i < NBIN; i += 256) hist[i] = 0;
    __syncthreads();
    int e0 = blockIdx.x * CHUNK;
    const int4* s4 = (const int4*)(eidx + e0);
    const int4* d4 = (const int4*)(eidx + E_EDGES + e0);
#pragma unroll
    for (int it = 0; it < 5; ++it) {
        int i = it * 256 + tid;
        int4 d = d4[i];
        atomicAdd(&hist[d.x >> BSHIFT], 1);
        atomicAdd(&hist[d.y >> BSHIFT], 1);
        atomicAdd(&hist[d.z >> BSHIFT], 1);
        atomicAdd(&hist[d.w >> BSHIFT], 1);
    }
    __syncthreads();
    for (int b = tid; b < NBIN; b += 256)
        cur[b] = atomicAdd(&gcnt[b], hist[b]);    // reserve dense per-(block,bin) range
    __syncthreads();
#pragma unroll
    for (int it = 0; it < 5; ++it) {
        int i = it * 256 + tid;
        int4 s = s4[i];
        int4 d = d4[i];
        int sv[4] = {s.x, s.y, s.z, s.w};
        int dv[4] = {d.x, d.y, d.z, d.w};
#pragma unroll
        for (int q = 0; q < 4; ++q) {
            int b = dv[q] >> BSHIFT;
            int slot = atomicAdd(&cur[b], 1);
            if (slot < BCAP)
                bbuf[(size_t)b * BCAP + slot] =
                    ((unsigned)(dv[q] & 255) << 17) | (unsigned)sv[q];
        }
    }
}

// ---------------- kernel 3: per-bin exact CSR (col + meta), LDS-local atomics -----
// R16: REVERTED to 256 threads (R13 version). R14's 512-thread variant landed in
// the pre-registered regression band (337 in 330-340): doubling threads doubled
// LDS-atomic contention on the same 256-entry hist at a net loss.
__global__ __launch_bounds__(256) void build_csr(const int* __restrict__ gcnt,
                                                 const unsigned* __restrict__ bbuf,
                                                 int* __restrict__ gpos,
                                                 int* __restrict__ col,
                                                 int2* __restrict__ meta) {
    __shared__ unsigned ebuf[BCAP];
    __shared__ int hist[NPB], pre[NPB], cur[NPB];
    __shared__ int sh_base;
    int b = blockIdx.x, tid = threadIdx.x;
    int mb = min(gcnt[b], BCAP);
    hist[tid] = 0;
    cur[tid] = 0;
    __syncthreads();
    for (int i = tid; i < mb; i += 256) {
        unsigned w = bbuf[(size_t)b * BCAP + i];
        ebuf[i] = w;
        atomicAdd(&hist[w >> 17], 1);
    }
    __syncthreads();
    if (tid < 64) {
        int a0 = hist[tid * 4 + 0], a1 = hist[tid * 4 + 1];
        int a2 = hist[tid * 4 + 2], a3 = hist[tid * 4 + 3];
        int s = a0 + a1 + a2 + a3;
        int t = s;
        for (int off = 1; off < 64; off <<= 1) {
            int v = __shfl_up(t, off, 64);
            if (tid >= off) t += v;
        }
        int excl = t - s;
        pre[tid * 4 + 0] = excl;
        pre[tid * 4 + 1] = excl + a0;
        pre[tid * 4 + 2] = excl + a0 + a1;
        pre[tid * 4 + 3] = excl + a0 + a1 + a2;
    }
    if (tid == 0) sh_base = atomicAdd(gpos, mb);
    __syncthreads();
    int gbase = sh_base;
    for (int i = tid; i < mb; i += 256) {
        unsigned w = ebuf[i];
        int l = (int)(w >> 17);
        int slot = atomicAdd(&cur[l], 1);
        col[gbase + pre[l] + slot] = (int)(w & 0x1FFFFu);
    }
    __syncthreads();
    int n = (b << BSHIFT) + tid;
    if (n < N_NODES) meta[n] = make_int2(gbase + pre[tid], hist[tid]);
}

// ---------------- kernel 4: h0b = bf16(x + sum x[src]), 4 rows per load instr -----
// Wave layout: 16 lanes x uint4 = one 256B row; groups g=0..3 cover 4 rows/instr.
// Self term ONLY in group 0. Cross-group partials folded by shfl_xor(16/32).
__global__ __launch_bounds__(256) void gather_h0(const unsigned* __restrict__ xb,
                                                 const int2* __restrict__ meta,
                                                 const int* __restrict__ col,
                                                 unsigned* __restrict__ h0b) {
    int lane = threadIdx.x & 63;
    int n = __builtin_amdgcn_readfirstlane(blockIdx.x * 4 + (threadIdx.x >> 6));
    int g = lane >> 4;         // row group within a 4-row load batch
    int li = lane & 15;        // uint4 index within the row (8 bf16 cols)
    int2 mt = meta[n];
    int base = mt.x, m = mt.y;

    const uint4* xb4 = (const uint4*)xb;
    float acc[8];
    if (g == 0) {              // self term exactly once across the fold
        uint4 sv = xb4[n * 16 + li];
        acc[0] = bf_lo(sv.x); acc[1] = bf_hi(sv.x);
        acc[2] = bf_lo(sv.y); acc[3] = bf_hi(sv.y);
        acc[4] = bf_lo(sv.z); acc[5] = bf_hi(sv.z);
        acc[6] = bf_lo(sv.w); acc[7] = bf_hi(sv.w);
    } else {
#pragma unroll
        for (int k = 0; k < 8; ++k) acc[k] = 0.f;
    }

    for (int c = 0; c < m; c += 64) {
        int rem = m - c;
        int lim = rem < 64 ? rem : 64;
        int idx = 0;
        if (lane < lim) idx = col[base + c + lane];   // one coalesced index load / 64
        int j = 0;
        for (; j + 32 <= lim; j += 32) {              // 32 rows via 8 dwordx4 in flight
            uint4 u[8];
#pragma unroll
            for (int t = 0; t < 8; ++t) {
                int s = __shfl(idx, j + t * 4 + g, 64);
                u[t] = xb4[s * 16 + li];
            }
#pragma unroll
            for (int t = 0; t < 8; ++t) {
                acc[0] += bf_lo(u[t].x); acc[1] += bf_hi(u[t].x);
                acc[2] += bf_lo(u[t].y); acc[3] += bf_hi(u[t].y);
                acc[4] += bf_lo(u[t].z); acc[5] += bf_hi(u[t].z);
                acc[6] += bf_lo(u[t].w); acc[7] += bf_hi(u[t].w);
            }
        }
        for (; j + 16 <= lim; j += 16) {              // 16 rows via 4 dwordx4 loads
            uint4 u[4];
#pragma unroll
            for (int t = 0; t < 4; ++t) {
                int s = __shfl(idx, j + t * 4 + g, 64);
                u[t] = xb4[s * 16 + li];
            }
#pragma unroll
            for (int t = 0; t < 4; ++t) {
                acc[0] += bf_lo(u[t].x); acc[1] += bf_hi(u[t].x);
                acc[2] += bf_lo(u[t].y); acc[3] += bf_hi(u[t].y);
                acc[4] += bf_lo(u[t].z); acc[5] += bf_hi(u[t].z);
                acc[6] += bf_lo(u[t].w); acc[7] += bf_hi(u[t].w);
            }
        }
        for (; j + 4 <= lim; j += 4) {                // 4 rows via 1 load
            int s = __shfl(idx, j + g, 64);
            uint4 u = xb4[s * 16 + li];
            acc[0] += bf_lo(u.x); acc[1] += bf_hi(u.x);
            acc[2] += bf_lo(u.y); acc[3] += bf_hi(u.y);
            acc[4] += bf_lo(u.z); acc[5] += bf_hi(u.z);
            acc[6] += bf_lo(u.w); acc[7] += bf_hi(u.w);
        }
        int tail = lim - j;                           // 0..3 rows
        if (tail > 0) {
            int s = __shfl(idx, j + (g < tail ? g : 0), 64);
            if (g < tail) {
                uint4 u = xb4[s * 16 + li];
                acc[0] += bf_lo(u.x); acc[1] += bf_hi(u.x);
                acc[2] += bf_lo(u.y); acc[3] += bf_hi(u.y);
                acc[4] += bf_lo(u.z); acc[5] += bf_hi(u.z);
                acc[6] += bf_lo(u.w); acc[7] += bf_hi(u.w);
            }
        }
    }
#pragma unroll
    for (int k = 0; k < 8; ++k) {                     // fold 4 row-groups
        acc[k] += __shfl_xor(acc[k], 16, 64);
        acc[k] += __shfl_xor(acc[k], 32, 64);
    }
    if (g == 0) {
        uint4 o;
        o.x = rne_bf16(acc[0]) | (rne_bf16(acc[1]) << 16);
        o.y = rne_bf16(acc[2]) | (rne_bf16(acc[3]) << 16);
        o.z = rne_bf16(acc[4]) | (rne_bf16(acc[5]) << 16);
        o.w = rne_bf16(acc[6]) | (rne_bf16(acc[7]) << 16);
        ((uint4*)h0b)[n * 16 + li] = o;
    }
}

// ---------------- kernel 5: fused 3-layer MLP via bf16 MFMA (reads bf16 h0b) ------
// R13: wt pre-transposed to fragment-load order -> 1KB contiguous weight loads.
// rt=4 (R10): 1564 waves, wave-private 64-row stripes, barrier-free.
#define HBW 136

__global__ __launch_bounds__(256, 2) void mlp_mfma(const unsigned* __restrict__ h0b,
                                                   float* __restrict__ out,
                                                   const unsigned short* __restrict__ wt,
                                                   const float* __restrict__ b1,
                                                   const float* __restrict__ b2,
                                                   const float* __restrict__ b3) {
    __shared__ unsigned short hb[256 * HBW];   // 69.6 KB
    int tid = threadIdx.x;
    int w = tid >> 6, lane = tid & 63;
    int m = lane & 15, quad = lane >> 4;
    int r0 = blockIdx.x * 256 + w * 64;        // wave-private 64-row stripe: no barriers

    for (int it = 0; it < 16; ++it) {          // stage 64 rows: 1024 uint4 per wave
        int flat = it * 64 + lane;
        int lr = flat >> 4, c4 = flat & 15;
        int gr = r0 + lr; if (gr >= N_NODES) gr = N_NODES - 1;
        uint4 v = ((const uint4*)h0b)[gr * 16 + c4];
        *(uint4*)&hb[(w * 64 + lr) * HBW + c4 * 8] = v;
    }

    const float* bias[3] = {b1, b2, b3};
    for (int l = 0; l < 3; ++l) {
        const unsigned short* W = wt + l * 16384;
        float bv[8];
#pragma unroll
        for (int ct = 0; ct < 8; ++ct) bv[ct] = bias[l][ct * 16 + m];

        f32x4 acc[4][8];
#pragma unroll
        for (int rt = 0; rt < 4; ++rt)
#pragma unroll
            for (int ct = 0; ct < 8; ++ct) acc[rt][ct] = (f32x4){0.f, 0.f, 0.f, 0.f};

#pragma unroll
        for (int ks = 0; ks < 4; ++ks) {
            bf16x8 a[4];
#pragma unroll
            for (int rt = 0; rt < 4; ++rt)
                a[rt] = *(const bf16x8*)&hb[(w * 64 + rt * 16 + m) * HBW + ks * 32 + quad * 8];
#pragma unroll
            for (int ct = 0; ct < 8; ++ct) {
                bf16x8 bf = *(const bf16x8*)&W[((ct * 4 + ks) << 9) + lane * 8];
#pragma unroll
                for (int rt = 0; rt < 4; ++rt)
                    acc[rt][ct] = __builtin_amdgcn_mfma_f32_16x16x32_bf16(a[rt], bf, acc[rt][ct], 0, 0, 0);
            }
        }

        if (l < 2) {
#pragma unroll
            for (int rt = 0; rt < 4; ++rt)
#pragma unroll
                for (int ct = 0; ct < 8; ++ct)
#pragma unroll
                    for (int r = 0; r < 4; ++r) {
                        float v = acc[rt][ct][r] + bv[ct];
                        v = v > 0.f ? v : 0.f;
                        hb[(w * 64 + rt * 16 + quad * 4 + r) * HBW + ct * 16 + m] =
                            (unsigned short)rne_bf16(v);
                    }
        } else {
#pragma unroll
            for (int rt = 0; rt < 4; ++rt)
#pragma unroll
                for (int r = 0; r < 4; ++r) {
                    int gr = r0 + rt * 16 + quad * 4 + r;
                    if (gr < N_NODES) {
#pragma unroll
                        for (int ct = 0; ct < 8; ++ct) {
                            float v = acc[rt][ct][r] + bv[ct];
                            out[(size_t)gr * 128 + ct * 16 + m] = v > 0.f ? v : 0.f;
                        }
                    }
                }
        }
    }
}

extern "C" void kernel_launch(void* const* d_in, const int* in_sizes, int n_in,
                              void* d_out, int out_size, void* d_ws, size_t ws_size,
                              hipStream_t stream) {
    const float* x  = (const float*)d_in[0];
    const float* W1 = (const float*)d_in[1];
    const float* b1 = (const float*)d_in[2];
    const float* W2 = (const float*)d_in[3];
    const float* b2 = (const float*)d_in[4];
    const float* W3 = (const float*)d_in[5];
    const float* b3 = (const float*)d_in[6];
    const int*  eidx = (const int*)d_in[7];
    float* out = (float*)d_out;

    // ws: [ctrl 4K: gcnt@0,gpos@2048][Wt 96K][meta][col][bbuf | h0b alias]  need 39.3 MB
    const size_t OFF_WT   = 4096;
    const size_t OFF_META = OFF_WT + 98304;
    const size_t OFF_COL  = OFF_META + 800256;
    const size_t OFF_BBUF = OFF_COL + (size_t)E_EDGES * 4;

    int* ctrl = (int*)d_ws;
    int* gcnt = (int*)d_ws;
    int* gpos = (int*)((char*)d_ws + 2048);
    unsigned short* wtb = (unsigned short*)((char*)d_ws + OFF_WT);
    int2* meta = (int2*)((char*)d_ws + OFF_META);
    int* col = (int*)((char*)d_ws + OFF_COL);
    unsigned* bbuf = (unsigned*)((char*)d_ws + OFF_BBUF);
    unsigned* h0b = bbuf;                       // alias: bbuf dead after build_csr
    unsigned* xb = (unsigned*)d_out;            // xb lives in d_out until mlp's final write

    prep<<<12500, 256, 0, stream>>>(x, W1, W2, W3, xb, wtb, ctrl);
    partition_edges<<<PBLK, 256, 0, stream>>>(eidx, gcnt, bbuf);
    build_csr<<<NBIN, 256, 0, stream>>>(gcnt, bbuf, gpos, col, meta);
    gather_h0<<<N_NODES / 4, 256, 0, stream>>>(xb, meta, col, h0b);
    mlp_mfma<<<(N_NODES + 255) / 256, 256, 0, stream>>>(h0b, out, wtb, b1, b2, b3);
}

// Round 19
// 322.514 us; speedup vs baseline: 1.0510x; 1.0510x over previous
//
#include <hip/hip_runtime.h>

#define N_NODES 100000
#define D 128
#define E_EDGES 3200000
#define BSHIFT 8
#define NPB 256                  // nodes per bin
#define NBIN 391                 // ceil(N_NODES / 256)
#define BCAP 8960                // per-bin capacity: mean 8192 + 8.5 sigma
#define PBLK 625
#define CHUNK 5120               // edges per partition block (int4-friendly)

typedef short bf16x8 __attribute__((ext_vector_type(8)));
typedef float f32x4 __attribute__((ext_vector_type(4)));

__device__ __forceinline__ unsigned rne_bf16(float f) {   // fp32 -> bf16 (RNE), low 16
    unsigned u = __float_as_uint(f);
    return (u + 0x7FFFu + ((u >> 16) & 1u)) >> 16;
}
__device__ __forceinline__ float bf_lo(unsigned u) { return __uint_as_float(u << 16); }
__device__ __forceinline__ float bf_hi(unsigned u) { return __uint_as_float(u & 0xFFFF0000u); }

// ---------------- kernel 1: xb = bf16(x), + Wt prep + ctrl zero (fused) -----------
// R13: weights in FRAGMENT-LOAD order (mlp weight loads fully coalesced).
// R14: float4 loads (16B/lane), 12500 blocks. KEPT — G13-textbook, low suspicion;
// R17 A/B isolates partition de-staging as the likely R14 regressor.
__global__ __launch_bounds__(256) void prep(const float* __restrict__ x,
                                            const float* __restrict__ W1,
                                            const float* __restrict__ W2,
                                            const float* __restrict__ W3,
                                            unsigned* __restrict__ xb,
                                            unsigned short* __restrict__ wt,
                                            int* __restrict__ ctrl) {
    int i = blockIdx.x * 256 + threadIdx.x;    // 12500 blocks: 3.2M float4
    float4 v = ((const float4*)x)[i];
    uint2 o;
    o.x = rne_bf16(v.x) | (rne_bf16(v.y) << 16);
    o.y = rne_bf16(v.z) | (rne_bf16(v.w) << 16);
    ((uint2*)xb)[i] = o;
    if (i < 1024) ctrl[i] = 0;                 // gcnt@0, gpos@dword512
    if (i < 3 * 16384) {
        int l = i >> 14, o2 = i & 16383;
        int j = o2 & 7, lane = (o2 >> 3) & 63, ks = (o2 >> 9) & 3, ct = (o2 >> 11) & 7;
        int m = lane & 15, quad = lane >> 4;
        int r = (ks * 32 + quad * 8 + j) * 128 + ct * 16 + m;
        const float* W = l == 0 ? W1 : (l == 1 ? W2 : W3);
        wt[l * 16384 + o2] = (unsigned short)rne_bf16(W[r]);
    }
}

// ---------------- kernel 2: bin edges by dst>>8 (int4 loads, LDS-staged) ----------
// R17: REVERTED to R13 LDS-staged version. R16 showed csr@512 was neutral, so
// the R14 +15us regression lives here (de-staging raised occupancy -> more
// concurrent global-atomic/scattered-store contention + 12.8MB extra fetch)
// or in prep (unlikely, G13-positive). Staged design is load-bearing.
__global__ __launch_bounds__(256) void partition_edges(const int* __restrict__ eidx,
                                                       int* __restrict__ gcnt,
                                                       unsigned* __restrict__ bbuf) {
    __shared__ int ssrc[CHUNK];    // 20 KB
    __shared__ int sdst[CHUNK];    // 20 KB
    __shared__ int hist[NBIN];
    __shared__ int cur[NBIN];
    int tid = threadIdx.x;
    for (int i = tid; i < NBIN; i += 256) hist[i] = 0;
    __syncthreads();
    int e0 = blockIdx.x * CHUNK;
    const int4* s4 = (const int4*)(eidx + e0);
    const int4* d4 = (const int4*)(eidx + E_EDGES + e0);
#pragma unroll
    for (int it = 0; it < 5; ++it) {
        int i = it * 256 + tid;
        int4 s = s4[i], d = d4[i];
        ((int4*)ssrc)[i] = s;
        ((int4*)sdst)[i] = d;
        atomicAdd(&hist[d.x >> BSHIFT], 1);
        atomicAdd(&hist[d.y >> BSHIFT], 1);
        atomicAdd(&hist[d.z >> BSHIFT], 1);
        atomicAdd(&hist[d.w >> BSHIFT], 1);
    }
    __syncthreads();
    for (int b = tid; b < NBIN; b += 256)
        cur[b] = atomicAdd(&gcnt[b], hist[b]);    // reserve dense per-(block,bin) range
    __syncthreads();
#pragma unroll
    for (int it = 0; it < 5; ++it) {
        int i = it * 256 + tid;
        int4 s = ((const int4*)ssrc)[i];
        int4 d = ((const int4*)sdst)[i];
        int sv[4] = {s.x, s.y, s.z, s.w};
        int dv[4] = {d.x, d.y, d.z, d.w};
#pragma unroll
        for (int q = 0; q < 4; ++q) {
            int b = dv[q] >> BSHIFT;
            int slot = atomicAdd(&cur[b], 1);
            if (slot < BCAP)
                bbuf[(size_t)b * BCAP + slot] =
                    ((unsigned)(dv[q] & 255) << 17) | (unsigned)sv[q];
        }
    }
}

// ---------------- kernel 3: per-bin exact CSR (col + meta), LDS-local atomics -----
// R16: 256 threads (R13 version) — csr@512 A/B'd neutral; keeping R13 form.
__global__ __launch_bounds__(256) void build_csr(const int* __restrict__ gcnt,
                                                 const unsigned* __restrict__ bbuf,
                                                 int* __restrict__ gpos,
                                                 int* __restrict__ col,
                                                 int2* __restrict__ meta) {
    __shared__ unsigned ebuf[BCAP];
    __shared__ int hist[NPB], pre[NPB], cur[NPB];
    __shared__ int sh_base;
    int b = blockIdx.x, tid = threadIdx.x;
    int mb = min(gcnt[b], BCAP);
    hist[tid] = 0;
    cur[tid] = 0;
    __syncthreads();
    for (int i = tid; i < mb; i += 256) {
        unsigned w = bbuf[(size_t)b * BCAP + i];
        ebuf[i] = w;
        atomicAdd(&hist[w >> 17], 1);
    }
    __syncthreads();
    if (tid < 64) {
        int a0 = hist[tid * 4 + 0], a1 = hist[tid * 4 + 1];
        int a2 = hist[tid * 4 + 2], a3 = hist[tid * 4 + 3];
        int s = a0 + a1 + a2 + a3;
        int t = s;
        for (int off = 1; off < 64; off <<= 1) {
            int v = __shfl_up(t, off, 64);
            if (tid >= off) t += v;
        }
        int excl = t - s;
        pre[tid * 4 + 0] = excl;
        pre[tid * 4 + 1] = excl + a0;
        pre[tid * 4 + 2] = excl + a0 + a1;
        pre[tid * 4 + 3] = excl + a0 + a1 + a2;
    }
    if (tid == 0) sh_base = atomicAdd(gpos, mb);
    __syncthreads();
    int gbase = sh_base;
    for (int i = tid; i < mb; i += 256) {
        unsigned w = ebuf[i];
        int l = (int)(w >> 17);
        int slot = atomicAdd(&cur[l], 1);
        col[gbase + pre[l] + slot] = (int)(w & 0x1FFFFu);
    }
    __syncthreads();
    int n = (b << BSHIFT) + tid;
    if (n < N_NODES) meta[n] = make_int2(gbase + pre[tid], hist[tid]);
}

// ---------------- kernel 4: h0b = bf16(x + sum x[src]), 4 rows per load instr -----
// Wave layout: 16 lanes x uint4 = one 256B row; groups g=0..3 cover 4 rows/instr.
// Self term ONLY in group 0. Cross-group partials folded by shfl_xor(16/32).
__global__ __launch_bounds__(256) void gather_h0(const unsigned* __restrict__ xb,
                                                 const int2* __restrict__ meta,
                                                 const int* __restrict__ col,
                                                 unsigned* __restrict__ h0b) {
    int lane = threadIdx.x & 63;
    int n = __builtin_amdgcn_readfirstlane(blockIdx.x * 4 + (threadIdx.x >> 6));
    int g = lane >> 4;         // row group within a 4-row load batch
    int li = lane & 15;        // uint4 index within the row (8 bf16 cols)
    int2 mt = meta[n];
    int base = mt.x, m = mt.y;

    const uint4* xb4 = (const uint4*)xb;
    float acc[8];
    if (g == 0) {              // self term exactly once across the fold
        uint4 sv = xb4[n * 16 + li];
        acc[0] = bf_lo(sv.x); acc[1] = bf_hi(sv.x);
        acc[2] = bf_lo(sv.y); acc[3] = bf_hi(sv.y);
        acc[4] = bf_lo(sv.z); acc[5] = bf_hi(sv.z);
        acc[6] = bf_lo(sv.w); acc[7] = bf_hi(sv.w);
    } else {
#pragma unroll
        for (int k = 0; k < 8; ++k) acc[k] = 0.f;
    }

    for (int c = 0; c < m; c += 64) {
        int rem = m - c;
        int lim = rem < 64 ? rem : 64;
        int idx = 0;
        if (lane < lim) idx = col[base + c + lane];   // one coalesced index load / 64
        int j = 0;
        for (; j + 32 <= lim; j += 32) {              // 32 rows via 8 dwordx4 in flight
            uint4 u[8];
#pragma unroll
            for (int t = 0; t < 8; ++t) {
                int s = __shfl(idx, j + t * 4 + g, 64);
                u[t] = xb4[s * 16 + li];
            }
#pragma unroll
            for (int t = 0; t < 8; ++t) {
                acc[0] += bf_lo(u[t].x); acc[1] += bf_hi(u[t].x);
                acc[2] += bf_lo(u[t].y); acc[3] += bf_hi(u[t].y);
                acc[4] += bf_lo(u[t].z); acc[5] += bf_hi(u[t].z);
                acc[6] += bf_lo(u[t].w); acc[7] += bf_hi(u[t].w);
            }
        }
        for (; j + 16 <= lim; j += 16) {              // 16 rows via 4 dwordx4 loads
            uint4 u[4];
#pragma unroll
            for (int t = 0; t < 4; ++t) {
                int s = __shfl(idx, j + t * 4 + g, 64);
                u[t] = xb4[s * 16 + li];
            }
#pragma unroll
            for (int t = 0; t < 4; ++t) {
                acc[0] += bf_lo(u[t].x); acc[1] += bf_hi(u[t].x);
                acc[2] += bf_lo(u[t].y); acc[3] += bf_hi(u[t].y);
                acc[4] += bf_lo(u[t].z); acc[5] += bf_hi(u[t].z);
                acc[6] += bf_lo(u[t].w); acc[7] += bf_hi(u[t].w);
            }
        }
        for (; j + 4 <= lim; j += 4) {                // 4 rows via 1 load
            int s = __shfl(idx, j + g, 64);
            uint4 u = xb4[s * 16 + li];
            acc[0] += bf_lo(u.x); acc[1] += bf_hi(u.x);
            acc[2] += bf_lo(u.y); acc[3] += bf_hi(u.y);
            acc[4] += bf_lo(u.z); acc[5] += bf_hi(u.z);
            acc[6] += bf_lo(u.w); acc[7] += bf_hi(u.w);
        }
        int tail = lim - j;                           // 0..3 rows
        if (tail > 0) {
            int s = __shfl(idx, j + (g < tail ? g : 0), 64);
            if (g < tail) {
                uint4 u = xb4[s * 16 + li];
                acc[0] += bf_lo(u.x); acc[1] += bf_hi(u.x);
                acc[2] += bf_lo(u.y); acc[3] += bf_hi(u.y);
                acc[4] += bf_lo(u.z); acc[5] += bf_hi(u.z);
                acc[6] += bf_lo(u.w); acc[7] += bf_hi(u.w);
            }
        }
    }
#pragma unroll
    for (int k = 0; k < 8; ++k) {                     // fold 4 row-groups
        acc[k] += __shfl_xor(acc[k], 16, 64);
        acc[k] += __shfl_xor(acc[k], 32, 64);
    }
    if (g == 0) {
        uint4 o;
        o.x = rne_bf16(acc[0]) | (rne_bf16(acc[1]) << 16);
        o.y = rne_bf16(acc[2]) | (rne_bf16(acc[3]) << 16);
        o.z = rne_bf16(acc[4]) | (rne_bf16(acc[5]) << 16);
        o.w = rne_bf16(acc[6]) | (rne_bf16(acc[7]) << 16);
        ((uint4*)h0b)[n * 16 + li] = o;
    }
}

// ---------------- kernel 5: fused 3-layer MLP via bf16 MFMA (reads bf16 h0b) ------
// R13: wt pre-transposed to fragment-load order -> 1KB contiguous weight loads.
// rt=4 (R10): 1564 waves, wave-private 64-row stripes, barrier-free.
#define HBW 136

__global__ __launch_bounds__(256, 2) void mlp_mfma(const unsigned* __restrict__ h0b,
                                                   float* __restrict__ out,
                                                   const unsigned short* __restrict__ wt,
                                                   const float* __restrict__ b1,
                                                   const float* __restrict__ b2,
                                                   const float* __restrict__ b3) {
    __shared__ unsigned short hb[256 * HBW];   // 69.6 KB
    int tid = threadIdx.x;
    int w = tid >> 6, lane = tid & 63;
    int m = lane & 15, quad = lane >> 4;
    int r0 = blockIdx.x * 256 + w * 64;        // wave-private 64-row stripe: no barriers

    for (int it = 0; it < 16; ++it) {          // stage 64 rows: 1024 uint4 per wave
        int flat = it * 64 + lane;
        int lr = flat >> 4, c4 = flat & 15;
        int gr = r0 + lr; if (gr >= N_NODES) gr = N_NODES - 1;
        uint4 v = ((const uint4*)h0b)[gr * 16 + c4];
        *(uint4*)&hb[(w * 64 + lr) * HBW + c4 * 8] = v;
    }

    const float* bias[3] = {b1, b2, b3};
    for (int l = 0; l < 3; ++l) {
        const unsigned short* W = wt + l * 16384;
        float bv[8];
#pragma unroll
        for (int ct = 0; ct < 8; ++ct) bv[ct] = bias[l][ct * 16 + m];

        f32x4 acc[4][8];
#pragma unroll
        for (int rt = 0; rt < 4; ++rt)
#pragma unroll
            for (int ct = 0; ct < 8; ++ct) acc[rt][ct] = (f32x4){0.f, 0.f, 0.f, 0.f};

#pragma unroll
        for (int ks = 0; ks < 4; ++ks) {
            bf16x8 a[4];
#pragma unroll
            for (int rt = 0; rt < 4; ++rt)
                a[rt] = *(const bf16x8*)&hb[(w * 64 + rt * 16 + m) * HBW + ks * 32 + quad * 8];
#pragma unroll
            for (int ct = 0; ct < 8; ++ct) {
                bf16x8 bf = *(const bf16x8*)&W[((ct * 4 + ks) << 9) + lane * 8];
#pragma unroll
                for (int rt = 0; rt < 4; ++rt)
                    acc[rt][ct] = __builtin_amdgcn_mfma_f32_16x16x32_bf16(a[rt], bf, acc[rt][ct], 0, 0, 0);
            }
        }

        if (l < 2) {
#pragma unroll
            for (int rt = 0; rt < 4; ++rt)
#pragma unroll
                for (int ct = 0; ct < 8; ++ct)
#pragma unroll
                    for (int r = 0; r < 4; ++r) {
                        float v = acc[rt][ct][r] + bv[ct];
                        v = v > 0.f ? v : 0.f;
                        hb[(w * 64 + rt * 16 + quad * 4 + r) * HBW + ct * 16 + m] =
                            (unsigned short)rne_bf16(v);
                    }
        } else {
#pragma unroll
            for (int rt = 0; rt < 4; ++rt)
#pragma unroll
                for (int r = 0; r < 4; ++r) {
                    int gr = r0 + rt * 16 + quad * 4 + r;
                    if (gr < N_NODES) {
#pragma unroll
                        for (int ct = 0; ct < 8; ++ct) {
                            float v = acc[rt][ct][r] + bv[ct];
                            out[(size_t)gr * 128 + ct * 16 + m] = v > 0.f ? v : 0.f;
                        }
                    }
                }
        }
    }
}

extern "C" void kernel_launch(void* const* d_in, const int* in_sizes, int n_in,
                              void* d_out, int out_size, void* d_ws, size_t ws_size,
                              hipStream_t stream) {
    const float* x  = (const float*)d_in[0];
    const float* W1 = (const float*)d_in[1];
    const float* b1 = (const float*)d_in[2];
    const float* W2 = (const float*)d_in[3];
    const float* b2 = (const float*)d_in[4];
    const float* W3 = (const float*)d_in[5];
    const float* b3 = (const float*)d_in[6];
    const int*  eidx = (const int*)d_in[7];
    float* out = (float*)d_out;

    // ws: [ctrl 4K: gcnt@0,gpos@2048][Wt 96K][meta][col][bbuf | h0b alias]  need 39.3 MB
    const size_t OFF_WT   = 4096;
    const size_t OFF_META = OFF_WT + 98304;
    const size_t OFF_COL  = OFF_META + 800256;
    const size_t OFF_BBUF = OFF_COL + (size_t)E_EDGES * 4;

    int* ctrl = (int*)d_ws;
    int* gcnt = (int*)d_ws;
    int* gpos = (int*)((char*)d_ws + 2048);
    unsigned short* wtb = (unsigned short*)((char*)d_ws + OFF_WT);
    int2* meta = (int2*)((char*)d_ws + OFF_META);
    int* col = (int*)((char*)d_ws + OFF_COL);
    unsigned* bbuf = (unsigned*)((char*)d_ws + OFF_BBUF);
    unsigned* h0b = bbuf;                       // alias: bbuf dead after build_csr
    unsigned* xb = (unsigned*)d_out;            // xb lives in d_out until mlp's final write

    prep<<<12500, 256, 0, stream>>>(x, W1, W2, W3, xb, wtb, ctrl);
    partition_edges<<<PBLK, 256, 0, stream>>>(eidx, gcnt, bbuf);
    build_csr<<<NBIN, 256, 0, stream>>>(gcnt, bbuf, gpos, col, meta);
    gather_h0<<<N_NODES / 4, 256, 0, stream>>>(xb, meta, col, h0b);
    mlp_mfma<<<(N_NODES + 255) / 256, 256, 0, stream>>>(h0b, out, wtb, b1, b2, b3);
}

// Round 20
// 319.234 us; speedup vs baseline: 1.0618x; 1.0103x over previous
//
#include <hip/hip_runtime.h>

#define N_NODES 100000
#define D 128
#define E_EDGES 3200000
#define BSHIFT 8
#define NPB 256                  // nodes per bin
#define NBIN 391                 // ceil(N_NODES / 256)
#define BCAP 8960                // per-bin capacity: mean 8192 + 8.5 sigma
#define PBLK 625
#define CHUNK 5120               // edges per partition block (int4-friendly)

typedef short bf16x8 __attribute__((ext_vector_type(8)));
typedef float f32x4 __attribute__((ext_vector_type(4)));

__device__ __forceinline__ unsigned rne_bf16(float f) {   // fp32 -> bf16 (RNE), low 16
    unsigned u = __float_as_uint(f);
    return (u + 0x7FFFu + ((u >> 16) & 1u)) >> 16;
}
__device__ __forceinline__ float bf_lo(unsigned u) { return __uint_as_float(u << 16); }
__device__ __forceinline__ float bf_hi(unsigned u) { return __uint_as_float(u & 0xFFFF0000u); }

// ------- kernel 1+2 FUSED (R19): partition blocks [0,625) + prep blocks [625,13125) -
// prep (writes xb/wt) and partition (reads eidx, writes gcnt/bbuf) touch disjoint
// data -> safe to co-dispatch. Partition blocks FIRST so their atomic/scatter
// phase starts immediately; HBM-streaming prep fills the machine around them
// (complementary pipes). ctrl zeroing moved to hipMemsetAsync (stream-ordered).
// Saves one ~5us launch + overlaps prep's ~15us under partition.
__global__ __launch_bounds__(256) void prep_partition(const float* __restrict__ x,
                                                      const float* __restrict__ W1,
                                                      const float* __restrict__ W2,
                                                      const float* __restrict__ W3,
                                                      unsigned* __restrict__ xb,
                                                      unsigned short* __restrict__ wt,
                                                      const int* __restrict__ eidx,
                                                      int* __restrict__ gcnt,
                                                      unsigned* __restrict__ bbuf) {
    __shared__ int ssrc[CHUNK];    // 20 KB
    __shared__ int sdst[CHUNK];    // 20 KB
    __shared__ int hist[NBIN];
    __shared__ int cur[NBIN];
    int tid = threadIdx.x;

    if (blockIdx.x >= PBLK) {      // ---- prep role (R13 wt transpose + R14 float4) --
        int i = (blockIdx.x - PBLK) * 256 + tid;   // 12500 blocks: 3.2M float4
        float4 v = ((const float4*)x)[i];
        uint2 o;
        o.x = rne_bf16(v.x) | (rne_bf16(v.y) << 16);
        o.y = rne_bf16(v.z) | (rne_bf16(v.w) << 16);
        ((uint2*)xb)[i] = o;
        if (i < 3 * 16384) {
            int l = i >> 14, o2 = i & 16383;
            int j = o2 & 7, lane = (o2 >> 3) & 63, ks = (o2 >> 9) & 3, ct = (o2 >> 11) & 7;
            int m = lane & 15, quad = lane >> 4;
            int r = (ks * 32 + quad * 8 + j) * 128 + ct * 16 + m;
            const float* W = l == 0 ? W1 : (l == 1 ? W2 : W3);
            wt[l * 16384 + o2] = (unsigned short)rne_bf16(W[r]);
        }
        return;
    }

    // ---- partition role (R13 LDS-staged form — staging is load-bearing, R17) ------
    for (int i = tid; i < NBIN; i += 256) hist[i] = 0;
    __syncthreads();
    int e0 = blockIdx.x * CHUNK;
    const int4* s4 = (const int4*)(eidx + e0);
    const int4* d4 = (const int4*)(eidx + E_EDGES + e0);
#pragma unroll
    for (int it = 0; it < 5; ++it) {
        int i = it * 256 + tid;
        int4 s = s4[i], d = d4[i];
        ((int4*)ssrc)[i] = s;
        ((int4*)sdst)[i] = d;
        atomicAdd(&hist[d.x >> BSHIFT], 1);
        atomicAdd(&hist[d.y >> BSHIFT], 1);
        atomicAdd(&hist[d.z >> BSHIFT], 1);
        atomicAdd(&hist[d.w >> BSHIFT], 1);
    }
    __syncthreads();
    for (int b = tid; b < NBIN; b += 256)
        cur[b] = atomicAdd(&gcnt[b], hist[b]);    // reserve dense per-(block,bin) range
    __syncthreads();
#pragma unroll
    for (int it = 0; it < 5; ++it) {
        int i = it * 256 + tid;
        int4 s = ((const int4*)ssrc)[i];
        int4 d = ((const int4*)sdst)[i];
        int sv[4] = {s.x, s.y, s.z, s.w};
        int dv[4] = {d.x, d.y, d.z, d.w};
#pragma unroll
        for (int q = 0; q < 4; ++q) {
            int b = dv[q] >> BSHIFT;
            int slot = atomicAdd(&cur[b], 1);
            if (slot < BCAP)
                bbuf[(size_t)b * BCAP + slot] =
                    ((unsigned)(dv[q] & 255) << 17) | (unsigned)sv[q];
        }
    }
}

// ---------------- kernel 3: per-bin exact CSR (col + meta), LDS-local atomics -----
// R16: 256 threads (R13 version) — csr@512 A/B'd neutral; keeping R13 form.
__global__ __launch_bounds__(256) void build_csr(const int* __restrict__ gcnt,
                                                 const unsigned* __restrict__ bbuf,
                                                 int* __restrict__ gpos,
                                                 int* __restrict__ col,
                                                 int2* __restrict__ meta) {
    __shared__ unsigned ebuf[BCAP];
    __shared__ int hist[NPB], pre[NPB], cur[NPB];
    __shared__ int sh_base;
    int b = blockIdx.x, tid = threadIdx.x;
    int mb = min(gcnt[b], BCAP);
    hist[tid] = 0;
    cur[tid] = 0;
    __syncthreads();
    for (int i = tid; i < mb; i += 256) {
        unsigned w = bbuf[(size_t)b * BCAP + i];
        ebuf[i] = w;
        atomicAdd(&hist[w >> 17], 1);
    }
    __syncthreads();
    if (tid < 64) {
        int a0 = hist[tid * 4 + 0], a1 = hist[tid * 4 + 1];
        int a2 = hist[tid * 4 + 2], a3 = hist[tid * 4 + 3];
        int s = a0 + a1 + a2 + a3;
        int t = s;
        for (int off = 1; off < 64; off <<= 1) {
            int v = __shfl_up(t, off, 64);
            if (tid >= off) t += v;
        }
        int excl = t - s;
        pre[tid * 4 + 0] = excl;
        pre[tid * 4 + 1] = excl + a0;
        pre[tid * 4 + 2] = excl + a0 + a1;
        pre[tid * 4 + 3] = excl + a0 + a1 + a2;
    }
    if (tid == 0) sh_base = atomicAdd(gpos, mb);
    __syncthreads();
    int gbase = sh_base;
    for (int i = tid; i < mb; i += 256) {
        unsigned w = ebuf[i];
        int l = (int)(w >> 17);
        int slot = atomicAdd(&cur[l], 1);
        col[gbase + pre[l] + slot] = (int)(w & 0x1FFFFu);
    }
    __syncthreads();
    int n = (b << BSHIFT) + tid;
    if (n < N_NODES) meta[n] = make_int2(gbase + pre[tid], hist[tid]);
}

// ---------------- kernel 4: h0b = bf16(x + sum x[src]), 4 rows per load instr -----
// Wave layout: 16 lanes x uint4 = one 256B row; groups g=0..3 cover 4 rows/instr.
// Self term ONLY in group 0. Cross-group partials folded by shfl_xor(16/32).
__global__ __launch_bounds__(256) void gather_h0(const unsigned* __restrict__ xb,
                                                 const int2* __restrict__ meta,
                                                 const int* __restrict__ col,
                                                 unsigned* __restrict__ h0b) {
    int lane = threadIdx.x & 63;
    int n = __builtin_amdgcn_readfirstlane(blockIdx.x * 4 + (threadIdx.x >> 6));
    int g = lane >> 4;         // row group within a 4-row load batch
    int li = lane & 15;        // uint4 index within the row (8 bf16 cols)
    int2 mt = meta[n];
    int base = mt.x, m = mt.y;

    const uint4* xb4 = (const uint4*)xb;
    float acc[8];
    if (g == 0) {              // self term exactly once across the fold
        uint4 sv = xb4[n * 16 + li];
        acc[0] = bf_lo(sv.x); acc[1] = bf_hi(sv.x);
        acc[2] = bf_lo(sv.y); acc[3] = bf_hi(sv.y);
        acc[4] = bf_lo(sv.z); acc[5] = bf_hi(sv.z);
        acc[6] = bf_lo(sv.w); acc[7] = bf_hi(sv.w);
    } else {
#pragma unroll
        for (int k = 0; k < 8; ++k) acc[k] = 0.f;
    }

    for (int c = 0; c < m; c += 64) {
        int rem = m - c;
        int lim = rem < 64 ? rem : 64;
        int idx = 0;
        if (lane < lim) idx = col[base + c + lane];   // one coalesced index load / 64
        int j = 0;
        for (; j + 32 <= lim; j += 32) {              // 32 rows via 8 dwordx4 in flight
            uint4 u[8];
#pragma unroll
            for (int t = 0; t < 8; ++t) {
                int s = __shfl(idx, j + t * 4 + g, 64);
                u[t] = xb4[s * 16 + li];
            }
#pragma unroll
            for (int t = 0; t < 8; ++t) {
                acc[0] += bf_lo(u[t].x); acc[1] += bf_hi(u[t].x);
                acc[2] += bf_lo(u[t].y); acc[3] += bf_hi(u[t].y);
                acc[4] += bf_lo(u[t].z); acc[5] += bf_hi(u[t].z);
                acc[6] += bf_lo(u[t].w); acc[7] += bf_hi(u[t].w);
            }
        }
        for (; j + 16 <= lim; j += 16) {              // 16 rows via 4 dwordx4 loads
            uint4 u[4];
#pragma unroll
            for (int t = 0; t < 4; ++t) {
                int s = __shfl(idx, j + t * 4 + g, 64);
                u[t] = xb4[s * 16 + li];
            }
#pragma unroll
            for (int t = 0; t < 4; ++t) {
                acc[0] += bf_lo(u[t].x); acc[1] += bf_hi(u[t].x);
                acc[2] += bf_lo(u[t].y); acc[3] += bf_hi(u[t].y);
                acc[4] += bf_lo(u[t].z); acc[5] += bf_hi(u[t].z);
                acc[6] += bf_lo(u[t].w); acc[7] += bf_hi(u[t].w);
            }
        }
        for (; j + 4 <= lim; j += 4) {                // 4 rows via 1 load
            int s = __shfl(idx, j + g, 64);
            uint4 u = xb4[s * 16 + li];
            acc[0] += bf_lo(u.x); acc[1] += bf_hi(u.x);
            acc[2] += bf_lo(u.y); acc[3] += bf_hi(u.y);
            acc[4] += bf_lo(u.z); acc[5] += bf_hi(u.z);
            acc[6] += bf_lo(u.w); acc[7] += bf_hi(u.w);
        }
        int tail = lim - j;                           // 0..3 rows
        if (tail > 0) {
            int s = __shfl(idx, j + (g < tail ? g : 0), 64);
            if (g < tail) {
                uint4 u = xb4[s * 16 + li];
                acc[0] += bf_lo(u.x); acc[1] += bf_hi(u.x);
                acc[2] += bf_lo(u.y); acc[3] += bf_hi(u.y);
                acc[4] += bf_lo(u.z); acc[5] += bf_hi(u.z);
                acc[6] += bf_lo(u.w); acc[7] += bf_hi(u.w);
            }
        }
    }
#pragma unroll
    for (int k = 0; k < 8; ++k) {                     // fold 4 row-groups
        acc[k] += __shfl_xor(acc[k], 16, 64);
        acc[k] += __shfl_xor(acc[k], 32, 64);
    }
    if (g == 0) {
        uint4 o;
        o.x = rne_bf16(acc[0]) | (rne_bf16(acc[1]) << 16);
        o.y = rne_bf16(acc[2]) | (rne_bf16(acc[3]) << 16);
        o.z = rne_bf16(acc[4]) | (rne_bf16(acc[5]) << 16);
        o.w = rne_bf16(acc[6]) | (rne_bf16(acc[7]) << 16);
        ((uint4*)h0b)[n * 16 + li] = o;
    }
}

// ---------------- kernel 5: fused 3-layer MLP via bf16 MFMA (reads bf16 h0b) ------
// R13: wt pre-transposed to fragment-load order -> 1KB contiguous weight loads.
// rt=4 (R10): 1564 waves, wave-private 64-row stripes, barrier-free.
#define HBW 136

__global__ __launch_bounds__(256, 2) void mlp_mfma(const unsigned* __restrict__ h0b,
                                                   float* __restrict__ out,
                                                   const unsigned short* __restrict__ wt,
                                                   const float* __restrict__ b1,
                                                   const float* __restrict__ b2,
                                                   const float* __restrict__ b3) {
    __shared__ unsigned short hb[256 * HBW];   // 69.6 KB
    int tid = threadIdx.x;
    int w = tid >> 6, lane = tid & 63;
    int m = lane & 15, quad = lane >> 4;
    int r0 = blockIdx.x * 256 + w * 64;        // wave-private 64-row stripe: no barriers

    for (int it = 0; it < 16; ++it) {          // stage 64 rows: 1024 uint4 per wave
        int flat = it * 64 + lane;
        int lr = flat >> 4, c4 = flat & 15;
        int gr = r0 + lr; if (gr >= N_NODES) gr = N_NODES - 1;
        uint4 v = ((const uint4*)h0b)[gr * 16 + c4];
        *(uint4*)&hb[(w * 64 + lr) * HBW + c4 * 8] = v;
    }

    const float* bias[3] = {b1, b2, b3};
    for (int l = 0; l < 3; ++l) {
        const unsigned short* W = wt + l * 16384;
        float bv[8];
#pragma unroll
        for (int ct = 0; ct < 8; ++ct) bv[ct] = bias[l][ct * 16 + m];

        f32x4 acc[4][8];
#pragma unroll
        for (int rt = 0; rt < 4; ++rt)
#pragma unroll
            for (int ct = 0; ct < 8; ++ct) acc[rt][ct] = (f32x4){0.f, 0.f, 0.f, 0.f};

#pragma unroll
        for (int ks = 0; ks < 4; ++ks) {
            bf16x8 a[4];
#pragma unroll
            for (int rt = 0; rt < 4; ++rt)
                a[rt] = *(const bf16x8*)&hb[(w * 64 + rt * 16 + m) * HBW + ks * 32 + quad * 8];
#pragma unroll
            for (int ct = 0; ct < 8; ++ct) {
                bf16x8 bf = *(const bf16x8*)&W[((ct * 4 + ks) << 9) + lane * 8];
#pragma unroll
                for (int rt = 0; rt < 4; ++rt)
                    acc[rt][ct] = __builtin_amdgcn_mfma_f32_16x16x32_bf16(a[rt], bf, acc[rt][ct], 0, 0, 0);
            }
        }

        if (l < 2) {
#pragma unroll
            for (int rt = 0; rt < 4; ++rt)
#pragma unroll
                for (int ct = 0; ct < 8; ++ct)
#pragma unroll
                    for (int r = 0; r < 4; ++r) {
                        float v = acc[rt][ct][r] + bv[ct];
                        v = v > 0.f ? v : 0.f;
                        hb[(w * 64 + rt * 16 + quad * 4 + r) * HBW + ct * 16 + m] =
                            (unsigned short)rne_bf16(v);
                    }
        } else {
#pragma unroll
            for (int rt = 0; rt < 4; ++rt)
#pragma unroll
                for (int r = 0; r < 4; ++r) {
                    int gr = r0 + rt * 16 + quad * 4 + r;
                    if (gr < N_NODES) {
#pragma unroll
                        for (int ct = 0; ct < 8; ++ct) {
                            float v = acc[rt][ct][r] + bv[ct];
                            out[(size_t)gr * 128 + ct * 16 + m] = v > 0.f ? v : 0.f;
                        }
                    }
                }
        }
    }
}

extern "C" void kernel_launch(void* const* d_in, const int* in_sizes, int n_in,
                              void* d_out, int out_size, void* d_ws, size_t ws_size,
                              hipStream_t stream) {
    const float* x  = (const float*)d_in[0];
    const float* W1 = (const float*)d_in[1];
    const float* b1 = (const float*)d_in[2];
    const float* W2 = (const float*)d_in[3];
    const float* b2 = (const float*)d_in[4];
    const float* W3 = (const float*)d_in[5];
    const float* b3 = (const float*)d_in[6];
    const int*  eidx = (const int*)d_in[7];
    float* out = (float*)d_out;

    // ws: [ctrl 4K: gcnt@0,gpos@2048][Wt 96K][meta][col][bbuf | h0b alias]  need 39.3 MB
    const size_t OFF_WT   = 4096;
    const size_t OFF_META = OFF_WT + 98304;
    const size_t OFF_COL  = OFF_META + 800256;
    const size_t OFF_BBUF = OFF_COL + (size_t)E_EDGES * 4;

    int* gcnt = (int*)d_ws;
    int* gpos = (int*)((char*)d_ws + 2048);
    unsigned short* wtb = (unsigned short*)((char*)d_ws + OFF_WT);
    int2* meta = (int2*)((char*)d_ws + OFF_META);
    int* col = (int*)((char*)d_ws + OFF_COL);
    unsigned* bbuf = (unsigned*)((char*)d_ws + OFF_BBUF);
    unsigned* h0b = bbuf;                       // alias: bbuf dead after build_csr
    unsigned* xb = (unsigned*)d_out;            // xb lives in d_out until mlp's final write

    hipMemsetAsync(d_ws, 0, 4096, stream);      // ctrl (gcnt + gpos) — stream-ordered
    prep_partition<<<PBLK + 12500, 256, 0, stream>>>(x, W1, W2, W3, xb, wtb,
                                                     eidx, gcnt, bbuf);
    build_csr<<<NBIN, 256, 0, stream>>>(gcnt, bbuf, gpos, col, meta);
    gather_h0<<<N_NODES / 4, 256, 0, stream>>>(xb, meta, col, h0b);
    mlp_mfma<<<(N_NODES + 255) / 256, 256, 0, stream>>>(h0b, out, wtb, b1, b2, b3);
}